// Round 9
// baseline (688.612 us; speedup 1.0000x reference)
//
#include <hip/hip_runtime.h>
#include <hip/hip_bf16.h>
#include <stdint.h>

#define E_DIMc 1024
#define A_DIMc 512
#define BATCHc 32
#define SEQc   2048
#define M_TOT  (BATCHc*SEQc)      // 65536
#define NEGINF -1e10f

// ws layout (float offsets) -- Xb buffer no longer needed (conv fused into gemm):
//   [0,      262144) : att partials, 4 slices of 65536
//   [262144, 278528) : decp (32 x 512)  (includes We_b + Wd_b)
//   [278528, 540672) : WeT bf16 [512][1024] (524288 ushort = 262144 floats)
#define WS_ATT  0
#define WS_DECP 262144
#define WS_WET  278528

typedef short  bf16x8 __attribute__((ext_vector_type(8)));
typedef float  f32x4  __attribute__((ext_vector_type(4)));

__device__ __forceinline__ uint32_t pack_bf16(float lo, float hi) {
    uint32_t a = __float_as_uint(lo) + 0x8000u;
    uint32_t b = __float_as_uint(hi) + 0x8000u;
    return __builtin_amdgcn_perm(b, a, 0x07060302u);  // [lo.hi16 | hi.hi16<<16]
}

__device__ __forceinline__ uint4 pack8(float4 f0, float4 f1) {
    uint4 pk;
    pk.x = pack_bf16(f0.x, f0.y);
    pk.y = pack_bf16(f0.z, f0.w);
    pk.z = pack_bf16(f1.x, f1.y);
    pk.w = pack_bf16(f1.z, f1.w);
    return pk;
}

__device__ __forceinline__ float fast_tanh(float x) {
    float e = __expf(2.0f * x);
    return 1.0f - 2.0f / (e + 1.0f);
}

// ---- transpose + convert We (1024x512 f32) -> WeT bf16 [512][1024] ----
__global__ void k_prep(const float* __restrict__ We, uint16_t* __restrict__ WeT) {
    int idx = blockIdx.x * 256 + threadIdx.x;     // 524288 total
    int a = idx & (A_DIMc - 1);                   // coalesced read (a fast)
    int k = idx >> 9;
    uint32_t u = __float_as_uint(We[(size_t)k * A_DIMc + a]) + 0x8000u;
    WeT[(size_t)a * E_DIMc + k] = (uint16_t)(u >> 16);
}

// ---- decoder projection: decp[b][a] = h[b]·Wd[:,a] + Wd_b[a] + We_b[a] ----
__global__ void k_dec(const float* __restrict__ h, const float* __restrict__ Wd,
                      const float* __restrict__ Wdb, const float* __restrict__ Web,
                      float* __restrict__ decp) {
    __shared__ float hs[E_DIMc];
    int b = blockIdx.x;
    int t = threadIdx.x;   // 512
    for (int i = t; i < E_DIMc; i += 512) hs[i] = h[(size_t)b * E_DIMc + i];
    __syncthreads();
    float acc = Wdb[t] + Web[t];
    #pragma unroll 8
    for (int k = 0; k < E_DIMc; ++k) acc += hs[k] * Wd[(size_t)k * A_DIMc + t];
    decp[(size_t)b * A_DIMc + t] = acc;
}

// ---- fused GEMM: reads X as f32, converts to bf16 in-register during staging ----
// R5 proved the line-coalesced mapping (4 lanes share one row's 64B window,
// XOR-swizzled LDS chunks) -> ~160 -> ~112us. R8 proved reg-staged dbuf is
// ~neutral (+6us: ds_write cost ~ latency hidden). R8's schedule is kept here
// because A must round-trip through VGPRs anyway for the f32->bf16 pack --
// the conversion is now free VALU under the MFMA phase, and the separate
// k_convX pass (384MB of HBM traffic, ~64us) is deleted. Numerics identical
// (same pack_bf16). A f32 reads: 4 lanes cover a row's 128B f32 window as
// 8x16B pieces (2 float4/lane) -> fully-consumed lines, still coalesced.
__global__ __launch_bounds__(256, 4)
void k_gemm_bf(const float* __restrict__ X,        // 65536 x 1024 f32
               const uint16_t* __restrict__ WeT,   // 512 x 1024 bf16
               const float* __restrict__ decp,
               const float* __restrict__ Wf,
               float* __restrict__ att_part)
{
    __shared__ uint16_t Alds[2][4096];   // 2 x 8 KB double buffer
    __shared__ uint16_t Blds[2][4096];   // 2 x 8 KB
    __shared__ float s_dec[128];
    __shared__ float s_wf[128];
    __shared__ float att_buf[256];

    const int bid = blockIdx.x;
    // XCD-sibling swizzle: the 4 blocks sharing an A-slab (same rb, nc=0..3)
    // all satisfy bid % 8 == x -> same XCD L2, dispatched within 32 bids.
    const int x  = bid & 7;
    const int g  = bid >> 3;
    const int nc = g & 3;
    const int rb = x * 64 + (g >> 2);
    const int rowBase = rb * 128;
    const int b = rowBase >> 11;
    const int t = threadIdx.x;
    const int lane = t & 63;
    const int w = t >> 6;
    const int wm = w & 1, wn = w >> 1;

    if (t < 128) {
        s_dec[t] = decp[(size_t)b * A_DIMc + nc * 128 + t];
        s_wf[t]  = Wf[nc * 128 + t];
    }

    f32x4 acc[4][4];
    #pragma unroll
    for (int i = 0; i < 4; i++)
        #pragma unroll
        for (int j = 0; j < 4; j++) acc[i][j] = (f32x4){0.f, 0.f, 0.f, 0.f};

    // chunk q -> global (row = q>>2, colblk = (q&3) ^ (row&3) ^ ((row>>2)&3));
    // q1 = q0+256 is row+64, same colblk (swizzle terms unchanged mod 16).
    const int row0 = t >> 2;
    const int cb0  = (t & 3) ^ (row0 & 3) ^ ((row0 >> 2) & 3);
    const float*    gAf = X   + (size_t)(rowBase + row0) * E_DIMc + cb0 * 8;
    const uint16_t* gB  = WeT + (size_t)(nc * 128 + row0) * E_DIMc + cb0 * 8;

    // read-side swizzle: fragment row r = 16*m + (lane&15), colblk = lane>>4:
    // chunk = r*4 + swz, swz = (lane>>4) ^ (lane&3) ^ ((lane>>2)&3).
    const int swz = (lane >> 4) ^ (lane & 3) ^ ((lane >> 2) & 3);
    const int arow = wm * 64 + (lane & 15);   // + mi*16 per fragment
    const int brow = wn * 64 + (lane & 15);   // + ni*16 per fragment

    float4 a00, a01, a10, a11;   // f32 A staging (next tile)
    uint4 rB0, rB1;              // bf16 B staging (next tile)

    // Staggered K start: sibling nc begins 2*nc iterations later (cyclic).
    // Prologue: tile 0 -> regs -> pack -> LDS buf 0.
    {
        const int k0 = ((nc * 2) & 31) * 32;
        a00 = *(const float4*)(gAf + k0);
        a01 = *(const float4*)(gAf + k0 + 4);
        a10 = *(const float4*)(gAf + 64 * E_DIMc + k0);
        a11 = *(const float4*)(gAf + 64 * E_DIMc + k0 + 4);
        rB0 = *(const uint4*)(gB + k0);
        rB1 = *(const uint4*)(gB + 64 * E_DIMc + k0);
        *(uint4*)&Alds[0][t * 8] = pack8(a00, a01);
        *(uint4*)&Alds[0][(t + 256) * 8] = pack8(a10, a11);
        *(uint4*)&Blds[0][t * 8] = rB0;
        *(uint4*)&Blds[0][(t + 256) * 8] = rB1;
    }
    __syncthreads();

    #pragma unroll 2          // p becomes compile-time: static LDS indexing
    for (int kt = 0; kt < 32; ++kt) {
        const int p = kt & 1;
        // (1) issue next tile's global loads FIRST -- they fly during compute
        if (kt < 31) {
            const int k1 = ((kt + 1 + nc * 2) & 31) * 32;
            a00 = *(const float4*)(gAf + k1);
            a01 = *(const float4*)(gAf + k1 + 4);
            a10 = *(const float4*)(gAf + 64 * E_DIMc + k1);
            a11 = *(const float4*)(gAf + 64 * E_DIMc + k1 + 4);
            rB0 = *(const uint4*)(gB + k1);
            rB1 = *(const uint4*)(gB + 64 * E_DIMc + k1);
        }
        // (2) compute current tile from LDS
        bf16x8 af[4], bf_[4];
        #pragma unroll
        for (int mi = 0; mi < 4; mi++)
            af[mi] = *(const bf16x8*)&Alds[p][((arow + mi * 16) * 4 + swz) * 8];
        #pragma unroll
        for (int ni = 0; ni < 4; ni++)
            bf_[ni] = *(const bf16x8*)&Blds[p][((brow + ni * 16) * 4 + swz) * 8];
        __builtin_amdgcn_s_setprio(1);
        #pragma unroll
        for (int mi = 0; mi < 4; mi++)
            #pragma unroll
            for (int ni = 0; ni < 4; ni++)
                acc[mi][ni] = __builtin_amdgcn_mfma_f32_16x16x32_bf16(af[mi], bf_[ni], acc[mi][ni], 0, 0, 0);
        __builtin_amdgcn_s_setprio(0);
        // (3) barrier: loads have had the whole compute phase to complete;
        //     also proves every wave is done reading buf[p^1]
        __syncthreads();
        // (4) pack + stage next tile into the other buffer, make visible
        if (kt < 31) {
            *(uint4*)&Alds[p ^ 1][t * 8] = pack8(a00, a01);
            *(uint4*)&Alds[p ^ 1][(t + 256) * 8] = pack8(a10, a11);
            *(uint4*)&Blds[p ^ 1][t * 8] = rB0;
            *(uint4*)&Blds[p ^ 1][(t + 256) * 8] = rB1;
            __syncthreads();
        }
    }

    float rowpart[4][4];
    #pragma unroll
    for (int mi = 0; mi < 4; mi++)
        #pragma unroll
        for (int r = 0; r < 4; r++) rowpart[mi][r] = 0.f;

    #pragma unroll
    for (int ni = 0; ni < 4; ni++) {
        int nl = wn * 64 + ni * 16 + (lane & 15);
        float dv = s_dec[nl], wfv = s_wf[nl];
        #pragma unroll
        for (int mi = 0; mi < 4; mi++)
            #pragma unroll
            for (int r = 0; r < 4; r++)
                rowpart[mi][r] += fast_tanh(acc[mi][ni][r] + dv) * wfv;
    }
    #pragma unroll
    for (int off = 1; off < 16; off <<= 1)
        #pragma unroll
        for (int mi = 0; mi < 4; mi++)
            #pragma unroll
            for (int r = 0; r < 4; r++)
                rowpart[mi][r] += __shfl_xor(rowpart[mi][r], off, 64);

    if ((lane & 15) == 0) {
        int q = lane >> 4;
        #pragma unroll
        for (int mi = 0; mi < 4; mi++)
            #pragma unroll
            for (int r = 0; r < 4; r++)
                att_buf[wn * 128 + wm * 64 + mi * 16 + q * 4 + r] = rowpart[mi][r];
    }
    __syncthreads();
    if (t < 128)
        att_part[(size_t)nc * M_TOT + rowBase + t] = att_buf[t] + att_buf[128 + t];
}

// ---- masked softmax over S per batch; also zero context region ----
__global__ void k_softmax(const float* __restrict__ att_part, const int* __restrict__ mask,
                          float* __restrict__ out) {
    __shared__ float red[8];
    int b = blockIdx.x, t = threadIdx.x;
    int w = t >> 6, lane = t & 63;
    float l[8];
    float mx = -3.4e38f;
    #pragma unroll
    for (int i = 0; i < 8; i++) {
        int idx = b * SEQc + i * 256 + t;
        float v = att_part[idx] + att_part[M_TOT + idx]
                + att_part[2 * M_TOT + idx] + att_part[3 * M_TOT + idx];
        if (mask[idx] == 0) v = NEGINF;
        l[i] = v;
        mx = fmaxf(mx, v);
    }
    #pragma unroll
    for (int off = 1; off < 64; off <<= 1) mx = fmaxf(mx, __shfl_xor(mx, off, 64));
    if (lane == 0) red[w] = mx;
    __syncthreads();
    mx = fmaxf(fmaxf(red[0], red[1]), fmaxf(red[2], red[3]));
    float sum = 0.f;
    #pragma unroll
    for (int i = 0; i < 8; i++) { l[i] = __expf(l[i] - mx); sum += l[i]; }
    #pragma unroll
    for (int off = 1; off < 64; off <<= 1) sum += __shfl_xor(sum, off, 64);
    if (lane == 0) red[4 + w] = sum;
    __syncthreads();
    sum = red[4] + red[5] + red[6] + red[7];
    float inv = 1.0f / sum;
    #pragma unroll
    for (int i = 0; i < 8; i++) out[b * SEQc + i * 256 + t] = l[i] * inv;
    // zero the context output region (re-poisoned to 0xAA before every call)
    *(float4*)&out[M_TOT + (size_t)b * E_DIMc + t * 4] = (float4){0.f, 0.f, 0.f, 0.f};
}

// ---- context from f32 X (L3-warm right after the gemm streamed it) ----
__global__ void k_context_f32(const float* __restrict__ X, const float* __restrict__ out_w,
                              float* __restrict__ out_ctx) {
    __shared__ float wsh[128];
    int b = blockIdx.x >> 4, sc = blockIdx.x & 15;
    int t = threadIdx.x;
    if (t < 128) wsh[t] = out_w[b * SEQc + sc * 128 + t];
    __syncthreads();
    float4 acc = {0.f, 0.f, 0.f, 0.f};
    const float* Xb = X + ((size_t)b * SEQc + sc * 128) * E_DIMc;
    #pragma unroll 4
    for (int s = 0; s < 128; ++s) {
        float wv = wsh[s];
        float4 xv = *(const float4*)(Xb + (size_t)s * E_DIMc + t * 4);
        acc.x += wv * xv.x; acc.y += wv * xv.y; acc.z += wv * xv.z; acc.w += wv * xv.w;
    }
    float* dst = out_ctx + (size_t)b * E_DIMc + t * 4;
    atomicAdd(dst + 0, acc.x);
    atomicAdd(dst + 1, acc.y);
    atomicAdd(dst + 2, acc.z);
    atomicAdd(dst + 3, acc.w);
}

extern "C" void kernel_launch(void* const* d_in, const int* in_sizes, int n_in,
                              void* d_out, int out_size, void* d_ws, size_t ws_size,
                              hipStream_t stream) {
    const float* X    = (const float*)d_in[0];
    const float* h    = (const float*)d_in[1];
    const int*   mask = (const int*)d_in[2];
    const float* We   = (const float*)d_in[3];
    const float* Web  = (const float*)d_in[4];
    const float* Wd   = (const float*)d_in[5];
    const float* Wdb  = (const float*)d_in[6];
    const float* Wf   = (const float*)d_in[7];
    // d_in[8] = Wf_b: uniform logit shift, cancels under softmax -> unused.
    float* out = (float*)d_out;
    float* ws  = (float*)d_ws;
    float*    att_part = ws + WS_ATT;
    float*    decp     = ws + WS_DECP;
    uint16_t* WeT      = (uint16_t*)(ws + WS_WET);

    hipLaunchKernelGGL(k_prep, dim3(2048), dim3(256), 0, stream, We, WeT);
    hipLaunchKernelGGL(k_dec,  dim3(32),   dim3(512), 0, stream, h, Wd, Wdb, Web, decp);
    hipLaunchKernelGGL(k_gemm_bf, dim3(2048), dim3(256), 0, stream, X, WeT, decp, Wf, att_part);
    hipLaunchKernelGGL(k_softmax, dim3(32), dim3(256), 0, stream, att_part, mask, out);
    hipLaunchKernelGGL(k_context_f32, dim3(512), dim3(256), 0, stream, X, out, out + M_TOT);
}

// Round 10
// 581.869 us; speedup vs baseline: 1.1834x; 1.1834x over previous
//
#include <hip/hip_runtime.h>
#include <hip/hip_bf16.h>
#include <stdint.h>

#define E_DIMc 1024
#define A_DIMc 512
#define BATCHc 32
#define SEQc   2048
#define M_TOT  (BATCHc*SEQc)      // 65536
#define NEGINF -1e10f

// ws layout (float offsets):
//   [0,      262144) : att partials, 4 slices of 65536
//   [262144, 278528) : decp (32 x 512)  (includes We_b + Wd_b)
//   [278528, 540672) : WeT bf16 [512][1024] (524288 ushort = 262144 floats)
//   [540672, ...   ) : Xb bf16 [65536][1024] (128 MB) -- big-ws path only
#define WS_ATT  0
#define WS_DECP 262144
#define WS_WET  278528
#define WS_XB   540672
#define WS_NEED_BYTES ((size_t)(WS_XB + (size_t)M_TOT * (E_DIMc/2)) * 4)  // ~136.4 MB

typedef short  bf16x8 __attribute__((ext_vector_type(8)));
typedef float  f32x4  __attribute__((ext_vector_type(4)));

__device__ __forceinline__ uint32_t pack_bf16(float lo, float hi) {
    uint32_t a = __float_as_uint(lo) + 0x8000u;
    uint32_t b = __float_as_uint(hi) + 0x8000u;
    return __builtin_amdgcn_perm(b, a, 0x07060302u);  // [lo.hi16 | hi.hi16<<16]
}

__device__ __forceinline__ float fast_tanh(float x) {
    float e = __expf(2.0f * x);
    return 1.0f - 2.0f / (e + 1.0f);
}

// ---- X (65536x1024 f32) -> Xb bf16, streaming ----
// R9 lesson: fusing this conversion into the GEMM (f32 A staging) caused
// ~300MB of scratch-spill traffic (WRITE_SIZE 1MB->305MB) and doubled
// compulsory fetch -- the separate bf16-once pass is strictly cheaper.
__global__ void k_convX(const float* __restrict__ X, uint16_t* __restrict__ Xb) {
    size_t g = (size_t)blockIdx.x * 256 + threadIdx.x;      // 8-float group index
    const size_t stride = (size_t)gridDim.x * 256;
    const size_t ngroups = (size_t)M_TOT * E_DIMc / 8;      // 8388608
    for (; g < ngroups; g += stride) {
        float4 f0 = ((const float4*)X)[2 * g];
        float4 f1 = ((const float4*)X)[2 * g + 1];
        uint4 pk;
        pk.x = pack_bf16(f0.x, f0.y);
        pk.y = pack_bf16(f0.z, f0.w);
        pk.z = pack_bf16(f1.x, f1.y);
        pk.w = pack_bf16(f1.z, f1.w);
        ((uint4*)Xb)[g] = pk;
    }
}

// ---- transpose + convert We (1024x512 f32) -> WeT bf16 [512][1024] ----
__global__ void k_prep(const float* __restrict__ We, uint16_t* __restrict__ WeT) {
    int idx = blockIdx.x * 256 + threadIdx.x;     // 524288 total
    int a = idx & (A_DIMc - 1);                   // coalesced read (a fast)
    int k = idx >> 9;
    uint32_t u = __float_as_uint(We[(size_t)k * A_DIMc + a]) + 0x8000u;
    WeT[(size_t)a * E_DIMc + k] = (uint16_t)(u >> 16);
}

// ---- decoder projection: decp[b][a] = h[b]·Wd[:,a] + Wd_b[a] + We_b[a] ----
__global__ void k_dec(const float* __restrict__ h, const float* __restrict__ Wd,
                      const float* __restrict__ Wdb, const float* __restrict__ Web,
                      float* __restrict__ decp) {
    __shared__ float hs[E_DIMc];
    int b = blockIdx.x;
    int t = threadIdx.x;   // 512
    for (int i = t; i < E_DIMc; i += 512) hs[i] = h[(size_t)b * E_DIMc + i];
    __syncthreads();
    float acc = Wdb[t] + Web[t];
    #pragma unroll 8
    for (int k = 0; k < E_DIMc; ++k) acc += hs[k] * Wd[(size_t)k * A_DIMc + t];
    decp[(size_t)b * A_DIMc + t] = acc;
}

// ---- pure-bf16 fused GEMM: coalesced lines + swizzled LDS + reg-staged dbuf ----
// R5 proved the transaction-rate fix (line-coalesced mapping, ~160->~112us).
// R8 added the reg-staged double buffer (bf16 staging = 16 VGPRs, no spill):
// measured 582us total, best known state. R9's f32-staging fusion regressed
// (+107us, scratch spill) and was reverted -- this is R8 verbatim.
__global__ __launch_bounds__(256, 4)
void k_gemm_bf(const uint16_t* __restrict__ Xb,     // 65536 x 1024 bf16
               const uint16_t* __restrict__ WeT,    // 512 x 1024 bf16
               const float* __restrict__ decp,
               const float* __restrict__ Wf,
               float* __restrict__ att_part)
{
    __shared__ uint16_t Alds[2][4096];   // 2 x 8 KB double buffer
    __shared__ uint16_t Blds[2][4096];   // 2 x 8 KB
    __shared__ float s_dec[128];
    __shared__ float s_wf[128];
    __shared__ float att_buf[256];

    const int bid = blockIdx.x;
    // XCD-sibling swizzle: the 4 blocks sharing an A-slab (same rb, nc=0..3)
    // all satisfy bid % 8 == x -> same XCD L2, dispatched within 32 bids.
    const int x  = bid & 7;
    const int g  = bid >> 3;
    const int nc = g & 3;
    const int rb = x * 64 + (g >> 2);
    const int rowBase = rb * 128;
    const int b = rowBase >> 11;
    const int t = threadIdx.x;
    const int lane = t & 63;
    const int w = t >> 6;
    const int wm = w & 1, wn = w >> 1;

    if (t < 128) {
        s_dec[t] = decp[(size_t)b * A_DIMc + nc * 128 + t];
        s_wf[t]  = Wf[nc * 128 + t];
    }

    f32x4 acc[4][4];
    #pragma unroll
    for (int i = 0; i < 4; i++)
        #pragma unroll
        for (int j = 0; j < 4; j++) acc[i][j] = (f32x4){0.f, 0.f, 0.f, 0.f};

    // chunk q -> global (row = q>>2, colblk = (q&3) ^ (row&3) ^ ((row>>2)&3));
    // q1 = q0+256 is row+64, same colblk (swizzle terms unchanged mod 16).
    const int row0 = t >> 2;
    const int cb0  = (t & 3) ^ (row0 & 3) ^ ((row0 >> 2) & 3);
    const uint16_t* gA = Xb  + (size_t)(rowBase + row0) * E_DIMc + cb0 * 8;
    const uint16_t* gB = WeT + (size_t)(nc * 128 + row0) * E_DIMc + cb0 * 8;

    // read-side swizzle: fragment row r = 16*m + (lane&15), colblk = lane>>4:
    // chunk = r*4 + swz, swz = (lane>>4) ^ (lane&3) ^ ((lane>>2)&3).
    const int swz = (lane >> 4) ^ (lane & 3) ^ ((lane >> 2) & 3);
    const int arow = wm * 64 + (lane & 15);   // + mi*16 per fragment
    const int brow = wn * 64 + (lane & 15);   // + ni*16 per fragment

    uint4 rA0, rA1, rB0, rB1;   // 16 VGPR staging for the next tile

    // Staggered K start: sibling nc begins 2*nc iterations later (cyclic).
    // Breaks the MSHR-merged lockstep where all 4 siblings miss the same
    // A-lines simultaneously; followers trail by 2 iters -> L2 hits.
    // Prologue: tile 0 -> regs -> LDS buf 0 (one-time exposed latency).
    {
        const int k0 = ((nc * 2) & 31) * 32;
        rA0 = *(const uint4*)(gA + k0);  rA1 = *(const uint4*)(gA + 64 * E_DIMc + k0);
        rB0 = *(const uint4*)(gB + k0);  rB1 = *(const uint4*)(gB + 64 * E_DIMc + k0);
        *(uint4*)&Alds[0][t * 8] = rA0;  *(uint4*)&Alds[0][(t + 256) * 8] = rA1;
        *(uint4*)&Blds[0][t * 8] = rB0;  *(uint4*)&Blds[0][(t + 256) * 8] = rB1;
    }
    __syncthreads();

    #pragma unroll 2          // p becomes compile-time: static LDS indexing
    for (int kt = 0; kt < 32; ++kt) {
        const int p = kt & 1;
        // (1) issue next tile's global loads FIRST -- they fly during compute
        if (kt < 31) {
            const int k1 = ((kt + 1 + nc * 2) & 31) * 32;
            rA0 = *(const uint4*)(gA + k1);  rA1 = *(const uint4*)(gA + 64 * E_DIMc + k1);
            rB0 = *(const uint4*)(gB + k1);  rB1 = *(const uint4*)(gB + 64 * E_DIMc + k1);
        }
        // (2) compute current tile from LDS
        bf16x8 af[4], bf_[4];
        #pragma unroll
        for (int mi = 0; mi < 4; mi++)
            af[mi] = *(const bf16x8*)&Alds[p][((arow + mi * 16) * 4 + swz) * 8];
        #pragma unroll
        for (int ni = 0; ni < 4; ni++)
            bf_[ni] = *(const bf16x8*)&Blds[p][((brow + ni * 16) * 4 + swz) * 8];
        __builtin_amdgcn_s_setprio(1);
        #pragma unroll
        for (int mi = 0; mi < 4; mi++)
            #pragma unroll
            for (int ni = 0; ni < 4; ni++)
                acc[mi][ni] = __builtin_amdgcn_mfma_f32_16x16x32_bf16(af[mi], bf_[ni], acc[mi][ni], 0, 0, 0);
        __builtin_amdgcn_s_setprio(0);
        // (3) barrier: loads have had the whole compute phase to complete;
        //     also proves every wave is done reading buf[p^1]
        __syncthreads();
        // (4) stage next tile into the other buffer, make visible
        if (kt < 31) {
            *(uint4*)&Alds[p ^ 1][t * 8] = rA0;  *(uint4*)&Alds[p ^ 1][(t + 256) * 8] = rA1;
            *(uint4*)&Blds[p ^ 1][t * 8] = rB0;  *(uint4*)&Blds[p ^ 1][(t + 256) * 8] = rB1;
            __syncthreads();
        }
    }

    float rowpart[4][4];
    #pragma unroll
    for (int mi = 0; mi < 4; mi++)
        #pragma unroll
        for (int r = 0; r < 4; r++) rowpart[mi][r] = 0.f;

    #pragma unroll
    for (int ni = 0; ni < 4; ni++) {
        int nl = wn * 64 + ni * 16 + (lane & 15);
        float dv = s_dec[nl], wfv = s_wf[nl];
        #pragma unroll
        for (int mi = 0; mi < 4; mi++)
            #pragma unroll
            for (int r = 0; r < 4; r++)
                rowpart[mi][r] += fast_tanh(acc[mi][ni][r] + dv) * wfv;
    }
    #pragma unroll
    for (int off = 1; off < 16; off <<= 1)
        #pragma unroll
        for (int mi = 0; mi < 4; mi++)
            #pragma unroll
            for (int r = 0; r < 4; r++)
                rowpart[mi][r] += __shfl_xor(rowpart[mi][r], off, 64);

    if ((lane & 15) == 0) {
        int q = lane >> 4;
        #pragma unroll
        for (int mi = 0; mi < 4; mi++)
            #pragma unroll
            for (int r = 0; r < 4; r++)
                att_buf[wn * 128 + wm * 64 + mi * 16 + q * 4 + r] = rowpart[mi][r];
    }
    __syncthreads();
    if (t < 128)
        att_part[(size_t)nc * M_TOT + rowBase + t] = att_buf[t] + att_buf[128 + t];
}

// ---- fallback fp32-A GEMM (round-1 version, used when ws is small) ----
__global__ __launch_bounds__(256, 2)
void k_gemm_f32(const float* __restrict__ X, const uint16_t* __restrict__ WeT,
                const float* __restrict__ decp, const float* __restrict__ Wf,
                float* __restrict__ att_part)
{
    __shared__ uint16_t Alds[4 * 128 * 8];
    __shared__ uint16_t Blds[4 * 128 * 8];
    __shared__ float s_dec[128];
    __shared__ float s_wf[128];
    __shared__ float att_buf[256];

    const int bid = blockIdx.x;
    const int nc = bid & 3;
    const int rowBase = (bid >> 2) * 128;
    const int b = rowBase >> 11;
    const int t = threadIdx.x;
    const int lane = t & 63;
    const int w = t >> 6;
    const int wm = w & 1, wn = w >> 1;

    if (t < 128) {
        s_dec[t] = decp[(size_t)b * A_DIMc + nc * 128 + t];
        s_wf[t]  = Wf[nc * 128 + t];
    }

    f32x4 acc[4][4];
    #pragma unroll
    for (int i = 0; i < 4; i++)
        #pragma unroll
        for (int j = 0; j < 4; j++) acc[i][j] = (f32x4){0.f, 0.f, 0.f, 0.f};

    const int c0 = t, c1 = t + 256;
    const float* gA0 = X + (size_t)(rowBase + (c0 & 127)) * E_DIMc + (c0 >> 7) * 8;
    const float* gA1 = X + (size_t)(rowBase + (c1 & 127)) * E_DIMc + (c1 >> 7) * 8;
    const int cB0 = (w * 2 + 0) * 64 + lane;
    const int cB1 = (w * 2 + 1) * 64 + lane;
    const uint16_t* gB0 = WeT + (size_t)(nc * 128 + (cB0 & 127)) * E_DIMc + (cB0 >> 7) * 8;
    const uint16_t* gB1 = WeT + (size_t)(nc * 128 + (cB1 & 127)) * E_DIMc + (cB1 >> 7) * 8;
    uint16_t* ldsB0 = &Blds[(w * 2 + 0) * 64 * 8];
    uint16_t* ldsB1 = &Blds[(w * 2 + 1) * 64 * 8];

    for (int k0 = 0; k0 < E_DIMc; k0 += 32) {
        __syncthreads();
        __builtin_amdgcn_global_load_lds(
            (const __attribute__((address_space(1))) void*)(gB0 + k0),
            (__attribute__((address_space(3))) void*)ldsB0, 16, 0, 0);
        __builtin_amdgcn_global_load_lds(
            (const __attribute__((address_space(1))) void*)(gB1 + k0),
            (__attribute__((address_space(3))) void*)ldsB1, 16, 0, 0);
        {
            float4 f0 = *(const float4*)(gA0 + k0);
            float4 f1 = *(const float4*)(gA0 + k0 + 4);
            uint4 pk;
            pk.x = pack_bf16(f0.x, f0.y); pk.y = pack_bf16(f0.z, f0.w);
            pk.z = pack_bf16(f1.x, f1.y); pk.w = pack_bf16(f1.z, f1.w);
            *(uint4*)&Alds[c0 * 8] = pk;
        }
        {
            float4 f0 = *(const float4*)(gA1 + k0);
            float4 f1 = *(const float4*)(gA1 + k0 + 4);
            uint4 pk;
            pk.x = pack_bf16(f0.x, f0.y); pk.y = pack_bf16(f0.z, f0.w);
            pk.z = pack_bf16(f1.x, f1.y); pk.w = pack_bf16(f1.z, f1.w);
            *(uint4*)&Alds[c1 * 8] = pk;
        }
        __syncthreads();

        bf16x8 af[4], bf_[4];
        #pragma unroll
        for (int mi = 0; mi < 4; mi++)
            af[mi] = *(const bf16x8*)&Alds[((lane >> 4) * 128 + wm * 64 + mi * 16 + (lane & 15)) * 8];
        #pragma unroll
        for (int ni = 0; ni < 4; ni++)
            bf_[ni] = *(const bf16x8*)&Blds[((lane >> 4) * 128 + wn * 64 + ni * 16 + (lane & 15)) * 8];
        #pragma unroll
        for (int mi = 0; mi < 4; mi++)
            #pragma unroll
            for (int ni = 0; ni < 4; ni++)
                acc[mi][ni] = __builtin_amdgcn_mfma_f32_16x16x32_bf16(af[mi], bf_[ni], acc[mi][ni], 0, 0, 0);
    }

    float rowpart[4][4];
    #pragma unroll
    for (int mi = 0; mi < 4; mi++)
        #pragma unroll
        for (int r = 0; r < 4; r++) rowpart[mi][r] = 0.f;
    #pragma unroll
    for (int ni = 0; ni < 4; ni++) {
        int nl = wn * 64 + ni * 16 + (lane & 15);
        float dv = s_dec[nl], wfv = s_wf[nl];
        #pragma unroll
        for (int mi = 0; mi < 4; mi++)
            #pragma unroll
            for (int r = 0; r < 4; r++)
                rowpart[mi][r] += fast_tanh(acc[mi][ni][r] + dv) * wfv;
    }
    #pragma unroll
    for (int off = 1; off < 16; off <<= 1)
        #pragma unroll
        for (int mi = 0; mi < 4; mi++)
            #pragma unroll
            for (int r = 0; r < 4; r++)
                rowpart[mi][r] += __shfl_xor(rowpart[mi][r], off, 64);
    if ((lane & 15) == 0) {
        int q = lane >> 4;
        #pragma unroll
        for (int mi = 0; mi < 4; mi++)
            #pragma unroll
            for (int r = 0; r < 4; r++)
                att_buf[wn * 128 + wm * 64 + mi * 16 + q * 4 + r] = rowpart[mi][r];
    }
    __syncthreads();
    if (t < 128)
        att_part[(size_t)nc * M_TOT + rowBase + t] = att_buf[t] + att_buf[128 + t];
}

// ---- masked softmax over S per batch; also zero context region ----
__global__ void k_softmax(const float* __restrict__ att_part, const int* __restrict__ mask,
                          float* __restrict__ out) {
    __shared__ float red[8];
    int b = blockIdx.x, t = threadIdx.x;
    int w = t >> 6, lane = t & 63;
    float l[8];
    float mx = -3.4e38f;
    #pragma unroll
    for (int i = 0; i < 8; i++) {
        int idx = b * SEQc + i * 256 + t;
        float v = att_part[idx] + att_part[M_TOT + idx]
                + att_part[2 * M_TOT + idx] + att_part[3 * M_TOT + idx];
        if (mask[idx] == 0) v = NEGINF;
        l[i] = v;
        mx = fmaxf(mx, v);
    }
    #pragma unroll
    for (int off = 1; off < 64; off <<= 1) mx = fmaxf(mx, __shfl_xor(mx, off, 64));
    if (lane == 0) red[w] = mx;
    __syncthreads();
    mx = fmaxf(fmaxf(red[0], red[1]), fmaxf(red[2], red[3]));
    float sum = 0.f;
    #pragma unroll
    for (int i = 0; i < 8; i++) { l[i] = __expf(l[i] - mx); sum += l[i]; }
    #pragma unroll
    for (int off = 1; off < 64; off <<= 1) sum += __shfl_xor(sum, off, 64);
    if (lane == 0) red[4 + w] = sum;
    __syncthreads();
    sum = red[4] + red[5] + red[6] + red[7];
    float inv = 1.0f / sum;
    #pragma unroll
    for (int i = 0; i < 8; i++) out[b * SEQc + i * 256 + t] = l[i] * inv;
    // zero the context output region (re-poisoned to 0xAA before every call)
    *(float4*)&out[M_TOT + (size_t)b * E_DIMc + t * 4] = (float4){0.f, 0.f, 0.f, 0.f};
}

// ---- context from bf16 Xb (128 MB, L3-hot after gemm) ----
__global__ void k_context_bf(const uint16_t* __restrict__ Xb, const float* __restrict__ out_w,
                             float* __restrict__ out_ctx) {
    __shared__ float wsh[128];
    __shared__ float part[128 * 8];
    int b = blockIdx.x >> 4, sc = blockIdx.x & 15;
    int t = threadIdx.x;
    if (t < 128) wsh[t] = out_w[b * SEQc + sc * 128 + t];
    __syncthreads();
    int ec = t & 127, sh = t >> 7;          // 8 e's per thread, 64 s-rows per half
    const uint16_t* Xp = Xb + ((size_t)(b * SEQc + sc * 128 + sh * 64)) * E_DIMc + ec * 8;
    const float* wp = &wsh[sh * 64];
    float acc[8] = {0.f,0.f,0.f,0.f,0.f,0.f,0.f,0.f};
    #pragma unroll 4
    for (int s = 0; s < 64; ++s) {
        float wv = wp[s];
        uint4 xv = *(const uint4*)(Xp + (size_t)s * E_DIMc);
        acc[0] += wv * __uint_as_float(xv.x << 16);
        acc[1] += wv * __uint_as_float(xv.x & 0xFFFF0000u);
        acc[2] += wv * __uint_as_float(xv.y << 16);
        acc[3] += wv * __uint_as_float(xv.y & 0xFFFF0000u);
        acc[4] += wv * __uint_as_float(xv.z << 16);
        acc[5] += wv * __uint_as_float(xv.z & 0xFFFF0000u);
        acc[6] += wv * __uint_as_float(xv.w << 16);
        acc[7] += wv * __uint_as_float(xv.w & 0xFFFF0000u);
    }
    if (sh == 1) {
        #pragma unroll
        for (int j = 0; j < 8; j++) part[ec * 8 + j] = acc[j];
    }
    __syncthreads();
    if (sh == 0) {
        float* dst = out_ctx + (size_t)b * E_DIMc + ec * 8;
        #pragma unroll
        for (int j = 0; j < 8; j++) atomicAdd(dst + j, acc[j] + part[ec * 8 + j]);
    }
}

// ---- fallback fp32 context ----
__global__ void k_context_f32(const float* __restrict__ X, const float* __restrict__ out_w,
                              float* __restrict__ out_ctx) {
    __shared__ float wsh[128];
    int b = blockIdx.x >> 4, sc = blockIdx.x & 15;
    int t = threadIdx.x;
    if (t < 128) wsh[t] = out_w[b * SEQc + sc * 128 + t];
    __syncthreads();
    float4 acc = {0.f, 0.f, 0.f, 0.f};
    const float* Xb = X + ((size_t)b * SEQc + sc * 128) * E_DIMc;
    #pragma unroll 4
    for (int s = 0; s < 128; ++s) {
        float wv = wsh[s];
        float4 xv = *(const float4*)(Xb + (size_t)s * E_DIMc + t * 4);
        acc.x += wv * xv.x; acc.y += wv * xv.y; acc.z += wv * xv.z; acc.w += wv * xv.w;
    }
    float* dst = out_ctx + (size_t)b * E_DIMc + t * 4;
    atomicAdd(dst + 0, acc.x);
    atomicAdd(dst + 1, acc.y);
    atomicAdd(dst + 2, acc.z);
    atomicAdd(dst + 3, acc.w);
}

extern "C" void kernel_launch(void* const* d_in, const int* in_sizes, int n_in,
                              void* d_out, int out_size, void* d_ws, size_t ws_size,
                              hipStream_t stream) {
    const float* X    = (const float*)d_in[0];
    const float* h    = (const float*)d_in[1];
    const int*   mask = (const int*)d_in[2];
    const float* We   = (const float*)d_in[3];
    const float* Web  = (const float*)d_in[4];
    const float* Wd   = (const float*)d_in[5];
    const float* Wdb  = (const float*)d_in[6];
    const float* Wf   = (const float*)d_in[7];
    // d_in[8] = Wf_b: uniform logit shift, cancels under softmax -> unused.
    float* out = (float*)d_out;
    float* ws  = (float*)d_ws;
    float*    att_part = ws + WS_ATT;
    float*    decp     = ws + WS_DECP;
    uint16_t* WeT      = (uint16_t*)(ws + WS_WET);
    uint16_t* Xb       = (uint16_t*)(ws + WS_XB);

    const bool big_ws = (ws_size >= WS_NEED_BYTES);   // constant across calls -> graph-safe

    hipLaunchKernelGGL(k_prep, dim3(2048), dim3(256), 0, stream, We, WeT);
    hipLaunchKernelGGL(k_dec,  dim3(32),   dim3(512), 0, stream, h, Wd, Wdb, Web, decp);
    if (big_ws) {
        hipLaunchKernelGGL(k_convX,   dim3(8192), dim3(256), 0, stream, X, Xb);
        hipLaunchKernelGGL(k_gemm_bf, dim3(2048), dim3(256), 0, stream, Xb, WeT, decp, Wf, att_part);
        hipLaunchKernelGGL(k_softmax, dim3(32), dim3(256), 0, stream, att_part, mask, out);
        hipLaunchKernelGGL(k_context_bf, dim3(512), dim3(256), 0, stream, Xb, out, out + M_TOT);
    } else {
        hipLaunchKernelGGL(k_gemm_f32, dim3(2048), dim3(256), 0, stream, X, WeT, decp, Wf, att_part);
        hipLaunchKernelGGL(k_softmax, dim3(32), dim3(256), 0, stream, att_part, mask, out);
        hipLaunchKernelGGL(k_context_f32, dim3(512), dim3(256), 0, stream, X, out, out + M_TOT);
    }
}